// Round 10
// baseline (949.351 us; speedup 1.0000x reference)
//
#include <hip/hip_runtime.h>
#include <stdint.h>

// EISepLSTM: x(T,B,I) -> ig GEMM -> 512-step EI recurrence -> out GEMM.
// T=512, B=128, I=H=O=512.
// Round 10: M=1 i8 recurrence, structurally specialized:
//  - A-tile is ONE row -> As[2][512] bytes; only lm==0 lanes ds_read (4-lane,
//    conflict-free); other lanes feed MFMA zeros.
//  - acc[j][0] already lives in lq==0 lanes at col j*16+lm -> NO redistribute;
//    epilogue runs in lq==0 lanes (4 cols each), params pre-gathered.
//  - ig/ei register double-buffered one step ahead (off critical path).
// 128 blocks x 512 threads, weights register-resident, 1 barrier/step.

typedef __attribute__((ext_vector_type(8))) short short8;
typedef __attribute__((ext_vector_type(4))) float f32x4;
typedef __attribute__((ext_vector_type(4))) int int4x;

__device__ __forceinline__ unsigned short f2b(float f) {
  unsigned int u = __float_as_uint(f);
  u = (u + 0x7fffu + ((u >> 16) & 1u)) >> 16;   // RNE
  return (unsigned short)u;
}
__device__ __forceinline__ float b2f(unsigned short s) {
  return __uint_as_float(((unsigned int)s) << 16);
}

// ---------------- prep: ei (plain), bf16 weight casts, c_last zeros --------
__global__ void prep_kernel(const float* __restrict__ gu,      // (T,H,2)
                            const float* __restrict__ logit,   // (H,2)
                            const float* __restrict__ win,     // (H,I)
                            const float* __restrict__ wout,    // (O,H)
                            float* __restrict__ ei,            // (T,H)
                            unsigned short* __restrict__ winb,
                            unsigned short* __restrict__ woutb,
                            float* __restrict__ c_last) {
  int i = blockIdx.x * 256 + threadIdx.x;          // 0 .. 262143
  int h = i & 511;
  float u0 = gu[2 * i], u1 = gu[2 * i + 1];
  float l0 = logit[2 * h], l1 = logit[2 * h + 1];
  float g0 = -logf(-logf(u0 + 1e-10f) + 1e-10f);
  float g1 = -logf(-logf(u1 + 1e-10f) + 1e-10f);
  // softmax2 diff == tanh(dz/2), dz = ((l0+g0)-(l1+g1))/tau
  float dz = ((l0 + g0) - (l1 + g1)) * 10.0f;
  ei[i] = tanhf(0.5f * dz);
  winb[i]  = f2b(win[i]);
  woutb[i] = f2b(wout[i]);
  if (i < 65536) c_last[i] = 0.0f;
}

// ---------------- Wrec row quantization: i8 with per-row scale -------------
__global__ void wquant_kernel(const float* __restrict__ wrec,  // (H,H)
                              char* __restrict__ wrec8,        // (H,H) i8
                              float* __restrict__ wscale) {    // (H)
  const int n = blockIdx.x;          // output row 0..511
  const int l = threadIdx.x;         // 0..63
  const float* row = wrec + (size_t)n * 512 + l * 8;
  float v[8];
  float m = 0.f;
#pragma unroll
  for (int e = 0; e < 8; ++e) {
    v[e] = fmaxf(row[e], 0.f);
    m = fmaxf(m, v[e]);
  }
#pragma unroll
  for (int off = 32; off >= 1; off >>= 1) m = fmaxf(m, __shfl_down(m, off));
  m = __shfl(m, 0);
  const float s = (m > 0.f) ? (m / 127.f) : 1.f;
  const float inv = 1.f / s;
  unsigned long long pk = 0;
#pragma unroll
  for (int e = 0; e < 8; ++e) {
    int q = (int)rintf(v[e] * inv);
    pk |= ((unsigned long long)(unsigned char)(char)q) << (8 * e);
  }
  *(unsigned long long*)(wrec8 + (size_t)n * 512 + l * 8) = pk;
  if (l == 0) wscale[n] = s;
}

// ---------------- GEMM: C[m,n] = sum_k A[m,k]*W[n,k] + bias[n] -------------
// A: M x 512 (f32 or bf16), W: 512 x 512 bf16 row-major, out f32 or bf16.
template <int A_F32, int OUT_BF16>
__global__ __launch_bounds__(256, 2) void gemm512(
    const void* __restrict__ Ap, const unsigned short* __restrict__ W,
    const float* __restrict__ bias, void* __restrict__ Cp) {
  __shared__ __align__(16) unsigned short Al[128][32];
  __shared__ __align__(16) unsigned short Bl[128][32];
  const int tid = threadIdx.x;
  const int w = tid >> 6, l = tid & 63;
  const int wr = w >> 1, wc = w & 1;
  const int lm = l & 15, lq = l >> 4;
  const size_t m0 = (size_t)blockIdx.x * 128;
  const int n0 = blockIdx.y * 128;
  const int r = tid >> 1;             // staging row 0..127
  const int sb = (tid & 1) << 1;      // staging slot base (16B slots): 0 or 2
  f32x4 acc[4][4] = {};

  for (int kt = 0; kt < 16; ++kt) {
    const int k0 = kt << 5;
    // stage A tile
    {
      char* dst = (char*)Al + r * 64;
      if (A_F32) {
        const float* A = (const float*)Ap + (m0 + r) * 512 + k0 + (sb << 3);
#pragma unroll
        for (int j = 0; j < 2; ++j) {
          float4 v0 = ((const float4*)A)[2 * j + 0];
          float4 v1 = ((const float4*)A)[2 * j + 1];
          short8 o;
          o[0] = (short)f2b(v0.x); o[1] = (short)f2b(v0.y);
          o[2] = (short)f2b(v0.z); o[3] = (short)f2b(v0.w);
          o[4] = (short)f2b(v1.x); o[5] = (short)f2b(v1.y);
          o[6] = (short)f2b(v1.z); o[7] = (short)f2b(v1.w);
          *(short8*)(dst + (((sb + j + (r >> 1)) & 3) << 4)) = o;
        }
      } else {
        const unsigned short* A =
            (const unsigned short*)Ap + (m0 + r) * 512 + k0 + (sb << 3);
#pragma unroll
        for (int j = 0; j < 2; ++j)
          *(short8*)(dst + (((sb + j + (r >> 1)) & 3) << 4)) =
              *(const short8*)(A + 8 * j);
      }
      // stage W tile
      const unsigned short* Wp = W + ((size_t)(n0 + r) << 9) + k0 + (sb << 3);
      char* dstB = (char*)Bl + r * 64;
#pragma unroll
      for (int j = 0; j < 2; ++j)
        *(short8*)(dstB + (((sb + j + (r >> 1)) & 3) << 4)) =
            *(const short8*)(Wp + 8 * j);
    }
    __syncthreads();
    short8 af[4], bf[4];
#pragma unroll
    for (int i = 0; i < 4; ++i) {
      int row = wr * 64 + i * 16 + lm;
      af[i] = *(const short8*)((char*)Al + row * 64 +
                               (((lq + (row >> 1)) & 3) << 4));
    }
#pragma unroll
    for (int j = 0; j < 4; ++j) {
      int row = wc * 64 + j * 16 + lm;
      bf[j] = *(const short8*)((char*)Bl + row * 64 +
                               (((lq + (row >> 1)) & 3) << 4));
    }
#pragma unroll
    for (int i = 0; i < 4; ++i)
#pragma unroll
      for (int j = 0; j < 4; ++j)
        acc[i][j] =
            __builtin_amdgcn_mfma_f32_16x16x32_bf16(af[i], bf[j], acc[i][j], 0, 0, 0);
    __syncthreads();
  }
  float bv[4];
#pragma unroll
  for (int j = 0; j < 4; ++j) bv[j] = bias[n0 + wc * 64 + j * 16 + lm];
#pragma unroll
  for (int i = 0; i < 4; ++i) {
#pragma unroll
    for (int r4 = 0; r4 < 4; ++r4) {
      size_t gm = m0 + wr * 64 + i * 16 + lq * 4 + r4;
#pragma unroll
      for (int j = 0; j < 4; ++j) {
        int gn = n0 + wc * 64 + j * 16 + lm;
        float v = acc[i][j][r4] + bv[j];
        if (OUT_BF16)
          ((unsigned short*)Cp)[(gm << 9) + gn] = f2b(v);
        else
          ((float*)Cp)[(gm << 9) + gn] = v;
      }
    }
  }
}

// ---------------- recurrence (M=1, 128 blocks x 8 waves, specialized) ------
// block g: batch row g. wave w: cols [64w,64w+64). As row = 512 B/parity.
// Only lm==0 lanes read As (A row 0); only lq==0 lanes run the epilogue,
// each handling cols {j*16+lm : j=0..3}.
__global__ __launch_bounds__(512, 1) void recur10_kernel(
    const unsigned short* __restrict__ ig,   // (T*B,512) bf16 plain
    const float* __restrict__ ei,            // (T,512) f32 plain
    const char* __restrict__ wrec8,          // (H,H) i8
    const float* __restrict__ wscale,        // (H)
    const float* __restrict__ rbias,         // (H)
    unsigned short* __restrict__ hs,         // (T*B,512) bf16 plain
    float* __restrict__ h_last) {            // (B,H) f32
  __shared__ __align__(16) char As[2][512];  // 1 KB total
  const int tid = threadIdx.x;
  const int g = blockIdx.x;            // batch row
  const int w = tid >> 6, l = tid & 63;
  const int lm = l & 15, lq = l >> 4;
  const int nbase = w << 6;
  const bool lmz = (lm == 0);

  // weights register-resident: bregs[kk][j] = Wrec8[nbase+j*16+lm][kk*64+lq*16..+16]
  int4x bregs[8][4];
#pragma unroll
  for (int kk = 0; kk < 8; ++kk)
#pragma unroll
    for (int j = 0; j < 4; ++j)
      bregs[kk][j] = *(const int4x*)(
          wrec8 + ((size_t)(nbase + j * 16 + lm) << 9) + (kk << 6) + (lq << 4));
  // per-epilogue-lane params for cols nbase + j*16 + lm (valid in lq==0 lanes;
  // loaded by all lanes uniformly over lq, harmless)
  float wsc[4], rb[4];
#pragma unroll
  for (int j = 0; j < 4; ++j) {
    wsc[j] = wscale[nbase + j * 16 + lm] * 0.0625f;   // * (1/16) a-scale
    rb[j]  = rbias[nbase + j * 16 + lm];
  }
  // zero both As parities (h0 = 0)
  if (tid < 256) ((int*)As)[tid] = 0;
  __syncthreads();

  // register double-buffer of ig[t] / ei[t+1] for this lane's 4 cols
  const unsigned short* igp0 = ig + ((size_t)g << 9) + nbase + lm;
  unsigned short igc[4];
  float eic[4];
#pragma unroll
  for (int j = 0; j < 4; ++j) {
    igc[j] = igp0[j * 16];
    eic[j] = ei[512 + nbase + j * 16 + lm];
  }

#pragma unroll 1
  for (int t = 0; t < 512; ++t) {
    const int par = t & 1, par2 = par ^ 1;
    // prefetch next step (off critical path)
    unsigned short ign[4] = {0, 0, 0, 0};
    float ein[4] = {0.f, 0.f, 0.f, 0.f};
    if (t < 511) {
#pragma unroll
      for (int j = 0; j < 4; ++j)
        ign[j] = __builtin_nontemporal_load(igp0 + (size_t)(t + 1) * 65536 +
                                            j * 16);
    }
    if (t < 510) {
#pragma unroll
      for (int j = 0; j < 4; ++j)
        ein[j] = ei[(size_t)(t + 2) * 512 + nbase + j * 16 + lm];
    }

    // K-loop: only lm==0 lanes carry A row 0; others contribute zeros
    int4x acc[4] = {};
#pragma unroll
    for (int kk = 0; kk < 8; ++kk) {
      int4x av = {0, 0, 0, 0};
      if (lmz)
        av = *(const int4x*)(&As[par][0] + (kk << 6) + (lq << 4));
#pragma unroll
      for (int j = 0; j < 4; ++j)
        acc[j] = __builtin_amdgcn_mfma_i32_16x16x64_i8(av, bregs[kk][j],
                                                       acc[j], 0, 0, 0);
    }
    // epilogue in lq==0 lanes: col = nbase + j*16 + lm, value acc[j][0]
    if (lq == 0) {
#pragma unroll
      for (int j = 0; j < 4; ++j) {
        const int n = nbase + (j << 4) + lm;
        float z = (float)acc[j][0] * wsc[j] + b2f(igc[j]) + rb[j];
        // fast softplus: max(z,0) + log(1+exp(-|z|)), native exp/log
        float az = fabsf(z);
        float h = fmaxf(z, 0.f) + __logf(1.f + __expf(-az));
        if (t < 511) {
          float a = h * eic[j] * 16.f;
          int ai = (int)rintf(fminf(fmaxf(a, -127.f), 127.f));
          As[par2][n] = (char)ai;
        }
        __builtin_nontemporal_store(
            f2b(h), hs + (((size_t)t * 128 + g) << 9) + n);
        if (t == 511) h_last[((size_t)g << 9) + n] = h;
      }
    }
#pragma unroll
    for (int j = 0; j < 4; ++j) {
      igc[j] = ign[j];
      eic[j] = ein[j];
    }
    __syncthreads();   // As[par2] visible before next step's K-loop
  }
}

// ---------------- launch ---------------------------------------------------
extern "C" void kernel_launch(void* const* d_in, const int* in_sizes, int n_in,
                              void* d_out, int out_size, void* d_ws,
                              size_t ws_size, hipStream_t stream) {
  const float* x     = (const float*)d_in[0];
  const float* gu    = (const float*)d_in[1];
  const float* Win   = (const float*)d_in[2];
  const float* bin   = (const float*)d_in[3];
  const float* Wrec  = (const float*)d_in[4];
  const float* rbias = (const float*)d_in[5];
  const float* elog  = (const float*)d_in[6];
  const float* Wout  = (const float*)d_in[7];
  const float* bout  = (const float*)d_in[8];

  char* ws = (char*)d_ws;
  float* ei             = (float*)ws;                        // 1 MB
  unsigned short* winb  = (unsigned short*)(ws + 4194304);   // 512 KB
  unsigned short* woutb = (unsigned short*)(ws + 4718592);   // 512 KB
  char* wrec8           = (char*)(ws + 5242880);             // 256 KB
  float* wscale         = (float*)(ws + 5505024);            // 2 KB
  unsigned short* igb   = (unsigned short*)(ws + 6291456);   // 64 MB
  unsigned short* hs    = (unsigned short*)(ws + 73400320);  // 64 MB

  float* outp  = (float*)d_out;            // (T,B,O) f32
  float* hlast = outp + 33554432;          // (B,H)
  float* clast = outp + 33554432 + 65536;  // (B,H) zeros

  prep_kernel<<<1024, 256, 0, stream>>>(gu, elog, Win, Wout, ei, winb, woutb,
                                        clast);
  wquant_kernel<<<512, 64, 0, stream>>>(Wrec, wrec8, wscale);
  gemm512<1, 1><<<dim3(512, 4), 256, 0, stream>>>(x, winb, bin, igb);
  recur10_kernel<<<128, 512, 0, stream>>>(igb, ei, wrec8, wscale, rbias, hs,
                                          hlast);
  gemm512<0, 0><<<dim3(512, 4), 256, 0, stream>>>(hs, woutb, bout, outp);
}

// Round 11
// 600.049 us; speedup vs baseline: 1.5821x; 1.5821x over previous
//
#include <hip/hip_runtime.h>
#include <stdint.h>

// EISepLSTM: x(T,B,I) -> ig GEMM -> 512-step EI recurrence -> out GEMM.
// T=512, B=128, I=H=O=512.
// Round 11: M=1 recurrence WITHOUT matrix cores. At M=1 an i8 MFMA tile is
// 94% waste (~16cy x 32/wave for 1 live row); instead each lane owns one
// output column n = tid and computes rec[n] = dot(a_t, Wrec8[n]) with
// v_dot4_i32_i8: 128 dots into 4 independent accum chains + 32 broadcast
// ds_read_b128 of the shared 512-B a-vector (uniform addr -> conflict-free,
// offset-immediate -> no address VALU). Epilogue/stores are 1 value/lane
// (r9's proven coalesced layout). 128 blocks x 512 threads, 1 barrier/step,
// no cross-block communication.

typedef __attribute__((ext_vector_type(8))) short short8;
typedef __attribute__((ext_vector_type(4))) float f32x4;
typedef __attribute__((ext_vector_type(4))) int int4x;

#if __has_builtin(__builtin_amdgcn_sdot4)
#define SDOT4(a, b, c) __builtin_amdgcn_sdot4((a), (b), (c), false)
#else
__device__ __forceinline__ int sdot4_asm(int a, int b, int c) {
  int r;
  asm volatile("v_dot4_i32_i8 %0, %1, %2, %3"
               : "=v"(r) : "v"(a), "v"(b), "v"(c));
  return r;
}
#define SDOT4(a, b, c) sdot4_asm((a), (b), (c))
#endif

__device__ __forceinline__ unsigned short f2b(float f) {
  unsigned int u = __float_as_uint(f);
  u = (u + 0x7fffu + ((u >> 16) & 1u)) >> 16;   // RNE
  return (unsigned short)u;
}
__device__ __forceinline__ float b2f(unsigned short s) {
  return __uint_as_float(((unsigned int)s) << 16);
}

// ---------------- prep: ei (plain), bf16 weight casts, c_last zeros --------
__global__ void prep_kernel(const float* __restrict__ gu,      // (T,H,2)
                            const float* __restrict__ logit,   // (H,2)
                            const float* __restrict__ win,     // (H,I)
                            const float* __restrict__ wout,    // (O,H)
                            float* __restrict__ ei,            // (T,H)
                            unsigned short* __restrict__ winb,
                            unsigned short* __restrict__ woutb,
                            float* __restrict__ c_last) {
  int i = blockIdx.x * 256 + threadIdx.x;          // 0 .. 262143
  int h = i & 511;
  float u0 = gu[2 * i], u1 = gu[2 * i + 1];
  float l0 = logit[2 * h], l1 = logit[2 * h + 1];
  float g0 = -logf(-logf(u0 + 1e-10f) + 1e-10f);
  float g1 = -logf(-logf(u1 + 1e-10f) + 1e-10f);
  // softmax2 diff == tanh(dz/2), dz = ((l0+g0)-(l1+g1))/tau
  float dz = ((l0 + g0) - (l1 + g1)) * 10.0f;
  ei[i] = tanhf(0.5f * dz);
  winb[i]  = f2b(win[i]);
  woutb[i] = f2b(wout[i]);
  if (i < 65536) c_last[i] = 0.0f;
}

// ---------------- Wrec row quantization: i8 with per-row scale -------------
__global__ void wquant_kernel(const float* __restrict__ wrec,  // (H,H)
                              char* __restrict__ wrec8,        // (H,H) i8
                              float* __restrict__ wscale) {    // (H)
  const int n = blockIdx.x;          // output row 0..511
  const int l = threadIdx.x;         // 0..63
  const float* row = wrec + (size_t)n * 512 + l * 8;
  float v[8];
  float m = 0.f;
#pragma unroll
  for (int e = 0; e < 8; ++e) {
    v[e] = fmaxf(row[e], 0.f);
    m = fmaxf(m, v[e]);
  }
#pragma unroll
  for (int off = 32; off >= 1; off >>= 1) m = fmaxf(m, __shfl_down(m, off));
  m = __shfl(m, 0);
  const float s = (m > 0.f) ? (m / 127.f) : 1.f;
  const float inv = 1.f / s;
  unsigned long long pk = 0;
#pragma unroll
  for (int e = 0; e < 8; ++e) {
    int q = (int)rintf(v[e] * inv);
    pk |= ((unsigned long long)(unsigned char)(char)q) << (8 * e);
  }
  *(unsigned long long*)(wrec8 + (size_t)n * 512 + l * 8) = pk;
  if (l == 0) wscale[n] = s;
}

// ---------------- GEMM: C[m,n] = sum_k A[m,k]*W[n,k] + bias[n] -------------
// A: M x 512 (f32 or bf16), W: 512 x 512 bf16 row-major, out f32 or bf16.
template <int A_F32, int OUT_BF16>
__global__ __launch_bounds__(256, 2) void gemm512(
    const void* __restrict__ Ap, const unsigned short* __restrict__ W,
    const float* __restrict__ bias, void* __restrict__ Cp) {
  __shared__ __align__(16) unsigned short Al[128][32];
  __shared__ __align__(16) unsigned short Bl[128][32];
  const int tid = threadIdx.x;
  const int w = tid >> 6, l = tid & 63;
  const int wr = w >> 1, wc = w & 1;
  const int lm = l & 15, lq = l >> 4;
  const size_t m0 = (size_t)blockIdx.x * 128;
  const int n0 = blockIdx.y * 128;
  const int r = tid >> 1;             // staging row 0..127
  const int sb = (tid & 1) << 1;      // staging slot base (16B slots): 0 or 2
  f32x4 acc[4][4] = {};

  for (int kt = 0; kt < 16; ++kt) {
    const int k0 = kt << 5;
    // stage A tile
    {
      char* dst = (char*)Al + r * 64;
      if (A_F32) {
        const float* A = (const float*)Ap + (m0 + r) * 512 + k0 + (sb << 3);
#pragma unroll
        for (int j = 0; j < 2; ++j) {
          float4 v0 = ((const float4*)A)[2 * j + 0];
          float4 v1 = ((const float4*)A)[2 * j + 1];
          short8 o;
          o[0] = (short)f2b(v0.x); o[1] = (short)f2b(v0.y);
          o[2] = (short)f2b(v0.z); o[3] = (short)f2b(v0.w);
          o[4] = (short)f2b(v1.x); o[5] = (short)f2b(v1.y);
          o[6] = (short)f2b(v1.z); o[7] = (short)f2b(v1.w);
          *(short8*)(dst + (((sb + j + (r >> 1)) & 3) << 4)) = o;
        }
      } else {
        const unsigned short* A =
            (const unsigned short*)Ap + (m0 + r) * 512 + k0 + (sb << 3);
#pragma unroll
        for (int j = 0; j < 2; ++j)
          *(short8*)(dst + (((sb + j + (r >> 1)) & 3) << 4)) =
              *(const short8*)(A + 8 * j);
      }
      // stage W tile
      const unsigned short* Wp = W + ((size_t)(n0 + r) << 9) + k0 + (sb << 3);
      char* dstB = (char*)Bl + r * 64;
#pragma unroll
      for (int j = 0; j < 2; ++j)
        *(short8*)(dstB + (((sb + j + (r >> 1)) & 3) << 4)) =
            *(const short8*)(Wp + 8 * j);
    }
    __syncthreads();
    short8 af[4], bf[4];
#pragma unroll
    for (int i = 0; i < 4; ++i) {
      int row = wr * 64 + i * 16 + lm;
      af[i] = *(const short8*)((char*)Al + row * 64 +
                               (((lq + (row >> 1)) & 3) << 4));
    }
#pragma unroll
    for (int j = 0; j < 4; ++j) {
      int row = wc * 64 + j * 16 + lm;
      bf[j] = *(const short8*)((char*)Bl + row * 64 +
                               (((lq + (row >> 1)) & 3) << 4));
    }
#pragma unroll
    for (int i = 0; i < 4; ++i)
#pragma unroll
      for (int j = 0; j < 4; ++j)
        acc[i][j] =
            __builtin_amdgcn_mfma_f32_16x16x32_bf16(af[i], bf[j], acc[i][j], 0, 0, 0);
    __syncthreads();
  }
  float bv[4];
#pragma unroll
  for (int j = 0; j < 4; ++j) bv[j] = bias[n0 + wc * 64 + j * 16 + lm];
#pragma unroll
  for (int i = 0; i < 4; ++i) {
#pragma unroll
    for (int r4 = 0; r4 < 4; ++r4) {
      size_t gm = m0 + wr * 64 + i * 16 + lq * 4 + r4;
#pragma unroll
      for (int j = 0; j < 4; ++j) {
        int gn = n0 + wc * 64 + j * 16 + lm;
        float v = acc[i][j][r4] + bv[j];
        if (OUT_BF16)
          ((unsigned short*)Cp)[(gm << 9) + gn] = f2b(v);
        else
          ((float*)Cp)[(gm << 9) + gn] = v;
      }
    }
  }
}

// ---------------- recurrence (M=1, sdot4, 128 blocks x 512 thr) ------------
// block g: batch row g. lane owns column n = tid. Weights: Wrec8 row n as
// 32 x int4 dwords in VGPRs. a_t: As[2][512] i8 in LDS, read via 32
// broadcast ds_read_b128. Epilogue 1 value/lane, coalesced stores.
__global__ __launch_bounds__(512, 2) void recur11_kernel(
    const unsigned short* __restrict__ ig,   // (T*B,512) bf16 plain
    const float* __restrict__ ei,            // (T,512) f32 plain
    const char* __restrict__ wrec8,          // (H,H) i8
    const float* __restrict__ wscale,        // (H)
    const float* __restrict__ rbias,         // (H)
    unsigned short* __restrict__ hs,         // (T*B,512) bf16 plain
    float* __restrict__ h_last) {            // (B,H) f32
  __shared__ __align__(16) char As[2][512];  // 1 KB
  const int tid = threadIdx.x;
  const int g = blockIdx.x;            // batch row
  const int n = tid;                   // this lane's output column

  // weights: row n as 32 x 4 dwords (one-time, L2-served)
  int4x wregs[32];
#pragma unroll
  for (int d = 0; d < 32; ++d)
    wregs[d] = *(const int4x*)(wrec8 + ((size_t)n << 9) + (d << 4));
  const float wscv = wscale[n] * 0.0625f;   // * (1/16) a-scale
  const float rbv  = rbias[n];
  // zero both As parities (h0 = 0)
  if (tid < 256) ((int*)As)[tid] = 0;
  __syncthreads();

  // register double-buffer of ig[t] / ei[t+1]
  const unsigned short* igp = ig + ((size_t)g << 9) + n;   // t-stride 65536
  unsigned short ig_cur = igp[0];
  float ei_cur = ei[512 + n];

#pragma unroll 1
  for (int t = 0; t < 512; ++t) {
    const int par = t & 1, par2 = par ^ 1;
    // prefetch next step (consumed next iteration; hides under dots)
    unsigned short ig_nxt = 0;
    float ei_nxt = 0.f;
    if (t < 511)
      ig_nxt = __builtin_nontemporal_load(igp + (size_t)(t + 1) * 65536);
    if (t < 510) ei_nxt = ei[(size_t)(t + 2) * 512 + n];

    // K-loop: rec[n] = dot(a_t, Wrec8[n]) via 128 sdot4 in 4 chains
    const char* ap = &As[par][0];
    int ac0 = 0, ac1 = 0, ac2 = 0, ac3 = 0;
#pragma unroll
    for (int d = 0; d < 32; ++d) {
      int4x a4 = *(const int4x*)(ap + (d << 4));   // broadcast read
      ac0 = SDOT4(a4[0], wregs[d][0], ac0);
      ac1 = SDOT4(a4[1], wregs[d][1], ac1);
      ac2 = SDOT4(a4[2], wregs[d][2], ac2);
      ac3 = SDOT4(a4[3], wregs[d][3], ac3);
    }
    const int acci = (ac0 + ac1) + (ac2 + ac3);

    // epilogue: 1 value per lane
    float z = (float)acci * wscv + b2f(ig_cur) + rbv;
    // fast softplus: max(z,0) + log(1+exp(-|z|)), native exp/log
    float az = fabsf(z);
    float h = fmaxf(z, 0.f) + __logf(1.f + __expf(-az));
    if (t < 511) {
      float a = h * ei_cur * 16.f;
      int ai = (int)rintf(fminf(fmaxf(a, -127.f), 127.f));
      As[par2][n] = (char)ai;
    }
    __builtin_nontemporal_store(f2b(h),
                                hs + (((size_t)t * 128 + g) << 9) + n);
    if (t == 511) h_last[((size_t)g << 9) + n] = h;
    ig_cur = ig_nxt;
    ei_cur = ei_nxt;
    __syncthreads();   // As[par2] visible before next step's K-loop
  }
}

// ---------------- launch ---------------------------------------------------
extern "C" void kernel_launch(void* const* d_in, const int* in_sizes, int n_in,
                              void* d_out, int out_size, void* d_ws,
                              size_t ws_size, hipStream_t stream) {
  const float* x     = (const float*)d_in[0];
  const float* gu    = (const float*)d_in[1];
  const float* Win   = (const float*)d_in[2];
  const float* bin   = (const float*)d_in[3];
  const float* Wrec  = (const float*)d_in[4];
  const float* rbias = (const float*)d_in[5];
  const float* elog  = (const float*)d_in[6];
  const float* Wout  = (const float*)d_in[7];
  const float* bout  = (const float*)d_in[8];

  char* ws = (char*)d_ws;
  float* ei             = (float*)ws;                        // 1 MB
  unsigned short* winb  = (unsigned short*)(ws + 4194304);   // 512 KB
  unsigned short* woutb = (unsigned short*)(ws + 4718592);   // 512 KB
  char* wrec8           = (char*)(ws + 5242880);             // 256 KB
  float* wscale         = (float*)(ws + 5505024);            // 2 KB
  unsigned short* igb   = (unsigned short*)(ws + 6291456);   // 64 MB
  unsigned short* hs    = (unsigned short*)(ws + 73400320);  // 64 MB

  float* outp  = (float*)d_out;            // (T,B,O) f32
  float* hlast = outp + 33554432;          // (B,H)
  float* clast = outp + 33554432 + 65536;  // (B,H) zeros

  prep_kernel<<<1024, 256, 0, stream>>>(gu, elog, Win, Wout, ei, winb, woutb,
                                        clast);
  wquant_kernel<<<512, 64, 0, stream>>>(Wrec, wrec8, wscale);
  gemm512<1, 1><<<dim3(512, 4), 256, 0, stream>>>(x, winb, bin, igb);
  recur11_kernel<<<128, 512, 0, stream>>>(igb, ei, wrec8, wscale, rbias, hs,
                                          hlast);
  gemm512<0, 0><<<dim3(512, 4), 256, 0, stream>>>(hs, woutb, bout, outp);
}